// Round 4
// baseline (170.255 us; speedup 1.0000x reference)
//
#include <hip/hip_runtime.h>

// S = 1024*1024, ranks [1,3,3,3,3,1].
#define SDIM (1024 * 1024)
#define GROUPS (SDIM / 4)             // float4 groups of s (262144)
#define GPT 2                         // float4-groups per thread in K1 (R2: GPT=1 41.5us, R3: GPT=4 44.4us)
#define CHUNKS (GROUPS / (256 * GPT)) // 512 chunks per plane -> 5120 blocks
#define NPLANE 10                     // TT0 (1 plane) + TT1..TT3 (3 planes each)

// K1: grid (CHUNKS, NPLANE). Each block computes a partial 3-vector:
//   part[plane][chunk][q] = sum_{s in chunk} z[s] * plane[s*3 + q]
// All 8 loads issued before any FMA -> 2x memory-level parallelism per thread
// (R3 lesson: the limiter is per-thread load concurrency, not the shuffle tail).
__global__ __launch_bounds__(256) void ftt_k1(
    const float* __restrict__ z,
    const float* __restrict__ t0,
    const float* __restrict__ t1,
    const float* __restrict__ t2,
    const float* __restrict__ t3,
    float* __restrict__ partials)   // [NPLANE][CHUNKS][4]
{
    const int plane = blockIdx.y;

    const float* base;
    if (plane == 0) {
        base = t0;
    } else {
        const int pk = plane - 1;
        const int k = pk / 3;                        // wave-uniform
        const float* tk = (k == 0) ? t1 : (k == 1) ? t2 : t3;
        base = tk + (pk % 3) * (3 * SDIM);
    }

    const int gA = blockIdx.x * (256 * GPT) + threadIdx.x;
    const int gB = gA + 256;

    // Issue all 8 loads up front (compiler keeps them in flight together).
    const float4 zA = reinterpret_cast<const float4*>(z)[gA];
    const float4 zB = reinterpret_cast<const float4*>(z)[gB];
    const float4* pA = reinterpret_cast<const float4*>(base + 12 * gA);
    const float4* pB = reinterpret_cast<const float4*>(base + 12 * gB);
    const float4 a0 = pA[0], a1 = pA[1], a2 = pA[2];
    const float4 b0 = pB[0], b1 = pB[1], b2 = pB[2];

    // acc[q] = sum_j z_j * tt[3j+q]; tt flat = c0.xyzw c1.xyzw c2.xyzw
    float s0, s1, s2;
    s0  = zA.x * a0.x + zA.y * a0.w + zA.z * a1.z + zA.w * a2.y;
    s1  = zA.x * a0.y + zA.y * a1.x + zA.z * a1.w + zA.w * a2.z;
    s2  = zA.x * a0.z + zA.y * a1.y + zA.z * a2.x + zA.w * a2.w;
    s0 += zB.x * b0.x + zB.y * b0.w + zB.z * b1.z + zB.w * b2.y;
    s1 += zB.x * b0.y + zB.y * b1.x + zB.z * b1.w + zB.w * b2.z;
    s2 += zB.x * b0.z + zB.y * b1.y + zB.z * b2.x + zB.w * b2.w;

    // wave (64) shuffle reduction
    #pragma unroll
    for (int off = 32; off > 0; off >>= 1) {
        s0 += __shfl_down(s0, off, 64);
        s1 += __shfl_down(s1, off, 64);
        s2 += __shfl_down(s2, off, 64);
    }

    __shared__ float red[4][3];
    const int lane = threadIdx.x & 63;
    const int wave = threadIdx.x >> 6;
    if (lane == 0) { red[wave][0] = s0; red[wave][1] = s1; red[wave][2] = s2; }
    __syncthreads();
    if (threadIdx.x < 3) {
        const int c = threadIdx.x;
        const float s = red[0][c] + red[1][c] + red[2][c] + red[3][c];
        partials[(plane * CHUNKS + blockIdx.x) * 4 + c] = s;
    }
}

// K2: reduce [NPLANE][CHUNKS] partial triples -> 30 sums -> f = V0@V1@V2@V3 (3 floats)
__global__ __launch_bounds__(256) void ftt_k2(
    const float* __restrict__ partials,
    float* __restrict__ fvec)
{
    __shared__ float red[NPLANE * 3][8];
    const int job = threadIdx.x >> 3;   // 0..31 (30 used): job = plane*3 + c
    const int sub = threadIdx.x & 7;    // 8 threads per job, CHUNKS/8 chunks each
    if (job < NPLANE * 3) {
        const int plane = job / 3, c = job % 3;
        float s = 0.0f;
        const int b0 = sub * (CHUNKS / 8);
        #pragma unroll 4
        for (int b = b0; b < b0 + (CHUNKS / 8); ++b)
            s += partials[(plane * CHUNKS + b) * 4 + c];
        red[job][sub] = s;
    }
    __syncthreads();

    if (threadIdx.x == 0) {
        float sum[NPLANE * 3];
        #pragma unroll
        for (int i = 0; i < NPLANE * 3; ++i) {
            float t = 0.0f;
            #pragma unroll
            for (int g = 0; g < 8; ++g) t += red[i][g];
            sum[i] = t;
        }
        float f0 = sum[0], f1 = sum[1], f2 = sum[2];
        #pragma unroll
        for (int k = 0; k < 3; ++k) {
            const float* V = &sum[3 + k * 9];   // V[r*3+q]
            const float n0 = f0 * V[0] + f1 * V[3] + f2 * V[6];
            const float n1 = f0 * V[1] + f1 * V[4] + f2 * V[7];
            const float n2 = f0 * V[2] + f1 * V[5] + f2 * V[8];
            f0 = n0; f1 = n1; f2 = n2;
        }
        fvec[0] = f0; fvec[1] = f1; fvec[2] = f2;
    }
}

// K3: out[s] = f0*TT4[0,s] + f1*TT4[1,s] + f2*TT4[2,s]   (TT4 is (3,S,1))
// 2 float4-groups per thread, all 6 loads issued up front.
__global__ __launch_bounds__(256) void ftt_k3(
    const float* __restrict__ t4,
    const float* __restrict__ fvec,
    float* __restrict__ out)
{
    const int i0 = (blockIdx.x * blockDim.x + threadIdx.x) * 2; // float4 index
    const float f0 = fvec[0], f1 = fvec[1], f2 = fvec[2];
    const float4* pa = reinterpret_cast<const float4*>(t4);
    const float4* pb = reinterpret_cast<const float4*>(t4 + SDIM);
    const float4* pc = reinterpret_cast<const float4*>(t4 + 2 * SDIM);
    const float4 aA = pa[i0], bA = pb[i0], cA = pc[i0];
    const float4 aB = pa[i0 + 1], bB = pb[i0 + 1], cB = pc[i0 + 1];
    float4 oA, oB;
    oA.x = f0 * aA.x + f1 * bA.x + f2 * cA.x;
    oA.y = f0 * aA.y + f1 * bA.y + f2 * cA.y;
    oA.z = f0 * aA.z + f1 * bA.z + f2 * cA.z;
    oA.w = f0 * aA.w + f1 * bA.w + f2 * cA.w;
    oB.x = f0 * aB.x + f1 * bB.x + f2 * cB.x;
    oB.y = f0 * aB.y + f1 * bB.y + f2 * cB.y;
    oB.z = f0 * aB.z + f1 * bB.z + f2 * cB.z;
    oB.w = f0 * aB.w + f1 * bB.w + f2 * cB.w;
    reinterpret_cast<float4*>(out)[i0] = oA;
    reinterpret_cast<float4*>(out)[i0 + 1] = oB;
}

extern "C" void kernel_launch(void* const* d_in, const int* in_sizes, int n_in,
                              void* d_out, int out_size, void* d_ws, size_t ws_size,
                              hipStream_t stream)
{
    const float* z  = (const float*)d_in[0];
    const float* t0 = (const float*)d_in[1];
    const float* t1 = (const float*)d_in[2];
    const float* t2 = (const float*)d_in[3];
    const float* t3 = (const float*)d_in[4];
    const float* t4 = (const float*)d_in[5];
    float* out = (float*)d_out;

    float* partials = (float*)d_ws;                      // NPLANE*CHUNKS*4 floats
    float* fvec     = partials + NPLANE * CHUNKS * 4;    // 3 floats

    ftt_k1<<<dim3(CHUNKS, NPLANE), 256, 0, stream>>>(z, t0, t1, t2, t3, partials);
    ftt_k2<<<1, 256, 0, stream>>>(partials, fvec);
    ftt_k3<<<SDIM / 4 / 256 / 2, 256, 0, stream>>>(t4, fvec, out);
}